// Round 2
// baseline (9237.910 us; speedup 1.0000x reference)
//
#include <hip/hip_runtime.h>

typedef __bf16 bf16;
typedef __bf16 bf16x8 __attribute__((ext_vector_type(8)));
typedef float  f32x4  __attribute__((ext_vector_type(4)));

__device__ __forceinline__ f32x4 mfma16(bf16x8 a, bf16x8 b, f32x4 c) {
  return __builtin_amdgcn_mfma_f32_16x16x32_bf16(a, b, c, 0, 0, 0);
}
__device__ __forceinline__ float sigm(float x)  { return 1.0f / (1.0f + __expf(-x)); }
__device__ __forceinline__ float tanh_(float x) { return 2.0f / (1.0f + __expf(-2.0f * x)) - 1.0f; }
__device__ __forceinline__ float softplus_(float x) {
  return fmaxf(x, 0.0f) + __logf(1.0f + __expf(-fabsf(x)));
}
__device__ __forceinline__ float leaky_(float x) { return x > 0.0f ? x : 0.01f * x; }

// ---------------- prep kernels (fp32 in -> bf16 out) ----------------

__global__ void k_transpose(const float* __restrict__ src, bf16* __restrict__ dst, int K, int N) {
  int i = blockIdx.x * 256 + threadIdx.x;
  if (i < K * N) { int k = i / N; int n = i - k * N; dst[n * K + k] = (bf16)src[i]; }
}

// P2T[n][i] = sum_j (pred[i][j] - delta_ij) * dp[j][n]   (N-major, pitch 256)
__global__ void k_p2(const float* __restrict__ pred, const float* __restrict__ dp, bf16* __restrict__ P2T) {
  int i = blockIdx.x * 256 + threadIdx.x;   // 65536
  int irow = i >> 8, n = i & 255;
  float acc = 0.0f;
  for (int j = 0; j < 256; ++j) {
    float p = pred[irow * 256 + j] - (j == irow ? 1.0f : 0.0f);
    acc += p * dp[j * 256 + n];
  }
  P2T[n * 256 + irow] = (bf16)acc;
}

// P1T[n][i] = sum_j (pred[i][j] - delta_ij) * g1[j][n]   (N-major, pitch 256)
__global__ void k_p1(const float* __restrict__ pred, const float* __restrict__ g1, bf16* __restrict__ P1T) {
  int i = blockIdx.x * 256 + threadIdx.x;   // 8192
  int irow = i >> 5, n = i & 31;
  float acc = 0.0f;
  for (int j = 0; j < 256; ++j) {
    float p = pred[irow * 256 + j] - (j == irow ? 1.0f : 0.0f);
    acc += p * g1[j * 32 + n];
  }
  P1T[n * 256 + irow] = (bf16)acc;
}

__global__ void k_cvec(const float* __restrict__ pred_b, const float* __restrict__ dp,
                       const float* __restrict__ g1, const float* __restrict__ g1_b,
                       float* __restrict__ c2f, float* __restrict__ c1f) {
  int n = threadIdx.x;  // 256 threads
  float acc = 0.0f;
  for (int j = 0; j < 256; ++j) acc += pred_b[j] * dp[j * 256 + n];
  c2f[n] = acc;
  if (n < 32) {
    float a2 = 0.0f;
    for (int j = 0; j < 256; ++j) a2 += pred_b[j] * g1[j * 32 + n];
    c1f[n] = a2 + g1_b[n];
  }
}

// ---------------- phase 1: x = leaky(leaky(LN(obs@obs_W+b))@enc_W+b)@pre_W+b) ----------------
// 4096 wgs x 256 thr, 64 rows per wg, writes x (fp32) into d_out (consumed by phase 2 before overwrite)

__global__ __launch_bounds__(256, 2) void k_phase1(
    const float* __restrict__ obs,
    const bf16* __restrict__ obs_WT, const bf16* __restrict__ enc_WT, const bf16* __restrict__ pre_WT,
    const float* __restrict__ obs_b, const float* __restrict__ enc_b, const float* __restrict__ pre_b,
    float* __restrict__ out)
{
  const int tid  = threadIdx.x;
  const int lane = tid & 63;
  const int w    = tid >> 6;       // wave 0..3
  const int n16  = lane & 15, quad = lane >> 4;
  const long R0  = (long)blockIdx.x * 64;

  __shared__ __align__(16) bf16 obsb[64][72];
  __shared__ __align__(16) bf16 ebuf[64][264];
  __shared__ __align__(16) bf16 e2buf[64][264];
  __shared__ float red[64][8];

  { // load obs tile 64x64 (fp32 -> bf16)
    int row = tid >> 2, col = (tid & 3) * 16;
    const float* src = obs + (R0 + row) * 64 + col;
    #pragma unroll
    for (int q = 0; q < 16; ++q) obsb[row][col + q] = (bf16)src[q];
  }
  __syncthreads();

  // G1: e0 = obs @ obs_W + obs_b  (K=64)
  {
    f32x4 acc[4][4] = {};
    #pragma unroll
    for (int ks = 0; ks < 2; ++ks) {
      bf16x8 a[4];
      #pragma unroll
      for (int mt = 0; mt < 4; ++mt) a[mt] = *(const bf16x8*)&obsb[mt * 16 + n16][ks * 32 + quad * 8];
      #pragma unroll
      for (int nt = 0; nt < 4; ++nt) {
        int ncol = (4 * w + nt) * 16 + n16;
        bf16x8 b = *(const bf16x8*)(obs_WT + ncol * 64 + ks * 32 + quad * 8);
        #pragma unroll
        for (int mt = 0; mt < 4; ++mt) acc[mt][nt] = mfma16(a[mt], b, acc[mt][nt]);
      }
    }
    #pragma unroll
    for (int nt = 0; nt < 4; ++nt) {
      int ncol = (4 * w + nt) * 16 + n16;
      float bb = obs_b[ncol];
      #pragma unroll
      for (int mt = 0; mt < 4; ++mt)
        #pragma unroll
        for (int reg = 0; reg < 4; ++reg)
          ebuf[mt * 16 + quad * 4 + reg][ncol] = (bf16)(acc[mt][nt][reg] + bb);
    }
  }
  __syncthreads();
  // LayerNorm over 256 (no affine)
  {
    int row = tid >> 2, qt = tid & 3;
    float s = 0, s2 = 0;
    for (int c = 0; c < 64; ++c) { float v = (float)ebuf[row][qt * 64 + c]; s += v; s2 += v * v; }
    red[row][qt] = s; red[row][4 + qt] = s2;
  }
  __syncthreads();
  if (tid < 64) {
    float s  = red[tid][0] + red[tid][1] + red[tid][2] + red[tid][3];
    float s2 = red[tid][4] + red[tid][5] + red[tid][6] + red[tid][7];
    float mu = s * (1.0f / 256.0f);
    float var = s2 * (1.0f / 256.0f) - mu * mu;
    red[tid][0] = mu; red[tid][1] = rsqrtf(var + 1e-5f);
  }
  __syncthreads();
  {
    int row = tid >> 2, qt = tid & 3;
    float mu = red[row][0], rstd = red[row][1];
    for (int c = 0; c < 64; ++c) {
      int cc = qt * 64 + c;
      ebuf[row][cc] = (bf16)(((float)ebuf[row][cc] - mu) * rstd);
    }
  }
  __syncthreads();
  // G2: e1 = leaky(e0n @ enc_W + enc_b)
  {
    f32x4 acc[4][4] = {};
    #pragma unroll
    for (int ks = 0; ks < 8; ++ks) {
      bf16x8 a[4];
      #pragma unroll
      for (int mt = 0; mt < 4; ++mt) a[mt] = *(const bf16x8*)&ebuf[mt * 16 + n16][ks * 32 + quad * 8];
      #pragma unroll
      for (int nt = 0; nt < 4; ++nt) {
        int ncol = (4 * w + nt) * 16 + n16;
        bf16x8 b = *(const bf16x8*)(enc_WT + ncol * 256 + ks * 32 + quad * 8);
        #pragma unroll
        for (int mt = 0; mt < 4; ++mt) acc[mt][nt] = mfma16(a[mt], b, acc[mt][nt]);
      }
    }
    #pragma unroll
    for (int nt = 0; nt < 4; ++nt) {
      int ncol = (4 * w + nt) * 16 + n16;
      float bb = enc_b[ncol];
      #pragma unroll
      for (int mt = 0; mt < 4; ++mt)
        #pragma unroll
        for (int reg = 0; reg < 4; ++reg)
          e2buf[mt * 16 + quad * 4 + reg][ncol] = (bf16)leaky_(acc[mt][nt][reg] + bb);
    }
  }
  __syncthreads();
  // G3: x = leaky(e1 @ pre_W + pre_b) -> global fp32 (d_out doubles as x buffer)
  {
    f32x4 acc[4][4] = {};
    #pragma unroll
    for (int ks = 0; ks < 8; ++ks) {
      bf16x8 a[4];
      #pragma unroll
      for (int mt = 0; mt < 4; ++mt) a[mt] = *(const bf16x8*)&e2buf[mt * 16 + n16][ks * 32 + quad * 8];
      #pragma unroll
      for (int nt = 0; nt < 4; ++nt) {
        int ncol = (4 * w + nt) * 16 + n16;
        bf16x8 b = *(const bf16x8*)(pre_WT + ncol * 256 + ks * 32 + quad * 8);
        #pragma unroll
        for (int mt = 0; mt < 4; ++mt) acc[mt][nt] = mfma16(a[mt], b, acc[mt][nt]);
      }
    }
    #pragma unroll
    for (int nt = 0; nt < 4; ++nt) {
      int ncol = (4 * w + nt) * 16 + n16;
      float bb = pre_b[ncol];
      #pragma unroll
      for (int mt = 0; mt < 4; ++mt)
        #pragma unroll
        for (int reg = 0; reg < 4; ++reg)
          out[(R0 + mt * 16 + quad * 4 + reg) * 256 + ncol] = leaky_(acc[mt][nt][reg] + bb);
    }
  }
}

// ---------------- phase 2: persistent recurrent scan ----------------
// 64 wgs x 512 thr (8 waves). wg owns rows b0..b0+15; wave w owns output cols [32w, 32w+32).
// h fp32 in LDS; per step: G1 [x|h]@Wrz and h@[P2|P1]; gates; G2 [x|r*h]@Wn; g chain; update.

__global__ __launch_bounds__(512, 2) void k_phase2(
    const float* __restrict__ h0,
    const int*  __restrict__ epoch_p,
    float* __restrict__ out,
    const bf16* __restrict__ WrzT, const bf16* __restrict__ WnT,
    const bf16* __restrict__ P2T,  const bf16* __restrict__ P1T,
    const bf16* __restrict__ g2T,  const bf16* __restrict__ g3T,
    const float* __restrict__ c2f, const float* __restrict__ c1f,
    const float* __restrict__ Wrz_b, const float* __restrict__ Wn_b,
    const float* __restrict__ g2_b,  const float* __restrict__ g3_b,
    const float* __restrict__ ln_g,  const float* __restrict__ ln_b)
{
  const int tid  = threadIdx.x;
  const int lane = tid & 63;
  const int w    = tid >> 6;        // wave 0..7
  const int n16  = lane & 15;
  const int quad = lane >> 4;
  const int b0   = blockIdx.x * 16;

  __shared__ __align__(16) float hs32[16][260];
  __shared__ __align__(16) bf16  Abuf[16][520];   // [x_t | h-then-rh]
  __shared__ __align__(16) float gbuf[16][36];
  __shared__ __align__(16) bf16  gact[16][40];
  __shared__ __align__(16) bf16  g2act[16][40];
  __shared__ float lngs[32], lnbs[32];

  { // init h state from h0 (fp32)
    int e = tid * 8; int row = e >> 8; int col = e & 255;
    const float* hp = h0 + (long)(b0 + row) * 256 + col;
    #pragma unroll
    for (int j = 0; j < 8; ++j) hs32[row][col + j] = hp[j];
  }
  if (tid < 32) { lngs[tid] = ln_g[tid]; lnbs[tid] = ln_b[tid]; }

  const int ep = *epoch_p;
  const float scale = fminf(1.0f, fmaxf(0.0f, ((float)ep - 5.0f) / 40.0f));

  const int colv[2] = { 32 * w + n16, 32 * w + 16 + n16 };
  float brz_r[2], brz_z[2], bwn[2], bg3e[2], bg3t[2], bg3a[2], c2v[2];
  #pragma unroll
  for (int i = 0; i < 2; ++i) {
    brz_r[i] = Wrz_b[colv[i]];
    brz_z[i] = Wrz_b[256 + colv[i]];
    bwn[i]   = Wn_b[colv[i]];
    bg3e[i]  = g3_b[colv[i]];
    bg3t[i]  = g3_b[256 + colv[i]];
    bg3a[i]  = g3_b[512 + colv[i]];
    c2v[i]   = c2f[colv[i]];
  }
  const float c1v   = (w < 2) ? c1f[w * 16 + n16] : 0.0f;
  const float g2bv0 = g2_b[n16];
  const float g2bv1 = g2_b[16 + n16];

  const bf16* Ab = &Abuf[n16][quad * 8];

  for (int t = 0; t < 256; ++t) {
    __syncthreads();   // protects hs32/Abuf across iterations
    // S1: stage x_t (fp32 from out, written by phase 1) and h (bf16) into Abuf
    {
      int e = tid * 8; int row = e >> 8; int col = e & 255;
      const float* xp = out + ((long)(b0 + row) * 256 + t) * 256 + col;
      bf16x8 xv;
      #pragma unroll
      for (int j = 0; j < 8; ++j) xv[j] = (bf16)xp[j];
      *(bf16x8*)&Abuf[row][col] = xv;
      bf16x8 hv;
      #pragma unroll
      for (int j = 0; j < 8; ++j) hv[j] = (bf16)hs32[row][col + j];
      *(bf16x8*)&Abuf[row][256 + col] = hv;
    }
    __syncthreads();
    // S2: G1a rz = [x|h]@Wrz (K=512), G1b dh/g = h@[P2|P1] (K=256)
    f32x4 accr[2] = {}, accz[2] = {}, accdh[2] = {}, accg = {};
    #pragma unroll
    for (int ks = 0; ks < 16; ++ks) {
      bf16x8 a = *(const bf16x8*)(Ab + ks * 32);
      const bf16* bp = WrzT + colv[0] * 512 + ks * 32 + quad * 8;
      accr[0] = mfma16(a, *(const bf16x8*)(bp            ), accr[0]);
      accr[1] = mfma16(a, *(const bf16x8*)(bp +  16 * 512), accr[1]);
      accz[0] = mfma16(a, *(const bf16x8*)(bp + 256 * 512), accz[0]);
      accz[1] = mfma16(a, *(const bf16x8*)(bp + 272 * 512), accz[1]);
    }
    #pragma unroll
    for (int ks = 0; ks < 8; ++ks) {
      bf16x8 a = *(const bf16x8*)(Ab + 256 + ks * 32);
      const bf16* bp = P2T + colv[0] * 256 + ks * 32 + quad * 8;
      accdh[0] = mfma16(a, *(const bf16x8*)(bp           ), accdh[0]);
      accdh[1] = mfma16(a, *(const bf16x8*)(bp + 16 * 256), accdh[1]);
      if (w < 2)
        accg = mfma16(a, *(const bf16x8*)(P1T + (w * 16 + n16) * 256 + ks * 32 + quad * 8), accg);
    }
    __syncthreads();   // all G1 reads of Abuf done before rh overwrite
    // S3: r,z gates; write r*h into Abuf[:,256:512]; gpre into gbuf
    float zv[2][4];
    #pragma unroll
    for (int reg = 0; reg < 4; ++reg) {
      int row = quad * 4 + reg;
      #pragma unroll
      for (int i = 0; i < 2; ++i) {
        float rv = sigm(accr[i][reg] + brz_r[i]);
        float hv = hs32[row][colv[i]];
        Abuf[row][256 + colv[i]] = (bf16)(rv * hv);
        zv[i][reg] = sigm(accz[i][reg] + brz_z[i]);
      }
      if (w < 2) gbuf[row][w * 16 + n16] = accg[reg] + c1v;
    }
    __syncthreads();
    // S4: LayerNorm(G=32) + affine + relu
    if (tid < 16) {
      float mu = 0, s2 = 0;
      #pragma unroll
      for (int c = 0; c < 32; ++c) { float v = gbuf[tid][c]; mu += v; s2 += v * v; }
      mu *= (1.0f / 32.0f);
      s2 = s2 * (1.0f / 32.0f) - mu * mu;
      float rstd = rsqrtf(s2 + 1e-5f);
      #pragma unroll
      for (int c = 0; c < 32; ++c) {
        float gn = (gbuf[tid][c] - mu) * rstd * lngs[c] + lnbs[c];
        gact[tid][c] = (bf16)fmaxf(gn, 0.0f);
      }
    }
    __syncthreads();
    // S5: g2 (wave 0 only)
    if (w == 0) {
      bf16x8 a = *(const bf16x8*)&gact[n16][quad * 8];
      f32x4 a0 = {}, a1 = {};
      a0 = mfma16(a, *(const bf16x8*)(g2T + n16 * 32 + quad * 8), a0);
      a1 = mfma16(a, *(const bf16x8*)(g2T + (16 + n16) * 32 + quad * 8), a1);
      #pragma unroll
      for (int reg = 0; reg < 4; ++reg) {
        int row = quad * 4 + reg;
        g2act[row][n16]      = (bf16)fmaxf(a0[reg] + g2bv0, 0.0f);
        g2act[row][16 + n16] = (bf16)fmaxf(a1[reg] + g2bv1, 0.0f);
      }
    }
    __syncthreads();
    // S6: G2 n = [x|r*h]@Wn (K=512); g3 (K=32)
    f32x4 accn[2] = {};
    #pragma unroll
    for (int ks = 0; ks < 16; ++ks) {
      bf16x8 a = *(const bf16x8*)(Ab + ks * 32);
      const bf16* bp = WnT + colv[0] * 512 + ks * 32 + quad * 8;
      accn[0] = mfma16(a, *(const bf16x8*)(bp           ), accn[0]);
      accn[1] = mfma16(a, *(const bf16x8*)(bp + 16 * 512), accn[1]);
    }
    f32x4 acce[2] = {}, acct[2] = {}, acca[2] = {};
    {
      bf16x8 a3 = *(const bf16x8*)&g2act[n16][quad * 8];
      const bf16* bp = g3T + colv[0] * 32 + quad * 8;
      acce[0] = mfma16(a3, *(const bf16x8*)(bp           ), acce[0]);
      acce[1] = mfma16(a3, *(const bf16x8*)(bp +  16 * 32), acce[1]);
      acct[0] = mfma16(a3, *(const bf16x8*)(bp + 256 * 32), acct[0]);
      acct[1] = mfma16(a3, *(const bf16x8*)(bp + 272 * 32), acct[1]);
      acca[0] = mfma16(a3, *(const bf16x8*)(bp + 512 * 32), acca[0]);
      acca[1] = mfma16(a3, *(const bf16x8*)(bp + 528 * 32), acca[1]);
    }
    // S7: final update + fp32 store
    #pragma unroll
    for (int reg = 0; reg < 4; ++reg) {
      int row = quad * 4 + reg;
      #pragma unroll
      for (int i = 0; i < 2; ++i) {
        float hv  = hs32[row][colv[i]];
        float dh  = accdh[i][reg] + c2v[i];
        float eta = sigm(acce[i][reg] + bg3e[i]);
        float th  = fminf(softplus_(acct[i][reg] + bg3t[i]), 5.0f);
        float al  = sigm(acca[i][reg] + bg3a[i]) * scale;
        float nn  = tanh_(accn[i][reg] + bwn[i]);
        float s   = fminf(fmaxf(eta * hv - th * dh, -5.0f), 5.0f);
        float htl = (1.0f - al) * hv + al * s;
        float hn  = zv[i][reg] * htl + (1.0f - zv[i][reg]) * nn;
        out[((long)(b0 + row) * 256 + t) * 256 + colv[i]] = hn;
        hs32[row][colv[i]] = hn;
      }
    }
  }
}

// ---------------- launch ----------------

extern "C" void kernel_launch(void* const* d_in, const int* in_sizes, int n_in,
                              void* d_out, int out_size, void* d_ws, size_t ws_size,
                              hipStream_t stream) {
  const float* obs    = (const float*)d_in[0];
  const float* h0     = (const float*)d_in[1];
  const int*   epoch  = (const int*)  d_in[2];
  const float* obs_W  = (const float*)d_in[3];
  const float* obs_b  = (const float*)d_in[4];
  const float* enc_W  = (const float*)d_in[5];
  const float* enc_b  = (const float*)d_in[6];
  const float* pre_W  = (const float*)d_in[7];
  const float* pre_b  = (const float*)d_in[8];
  const float* pred_W = (const float*)d_in[9];
  const float* pred_b = (const float*)d_in[10];
  const float* Wrz_W  = (const float*)d_in[11];
  const float* Wrz_b  = (const float*)d_in[12];
  const float* Wn_W   = (const float*)d_in[13];
  const float* Wn_b   = (const float*)d_in[14];
  const float* g1_W   = (const float*)d_in[15];
  const float* g1_b   = (const float*)d_in[16];
  const float* ln_g   = (const float*)d_in[17];
  const float* ln_b   = (const float*)d_in[18];
  const float* g2_W   = (const float*)d_in[19];
  const float* g2_b   = (const float*)d_in[20];
  const float* g3_W   = (const float*)d_in[21];
  const float* g3_b   = (const float*)d_in[22];
  const float* dp_W   = (const float*)d_in[23];

  bf16* W = (bf16*)d_ws;
  bf16* WrzT  = W + 0;        // 262144
  bf16* WnT   = W + 262144;   // 131072
  bf16* P2T   = W + 393216;   // 65536
  bf16* P1T   = W + 458752;   // 8192
  bf16* g2T   = W + 466944;   // 1024
  bf16* g3T   = W + 467968;   // 24576
  bf16* obsWT = W + 492544;   // 16384
  bf16* encWT = W + 508928;   // 65536
  bf16* preWT = W + 574464;   // 65536
  float* c2f  = (float*)((char*)d_ws + 1280000);  // 256 f32
  float* c1f  = (float*)((char*)d_ws + 1281024);  // 32 f32
  float* out = (float*)d_out;

  k_transpose<<<1024, 256, 0, stream>>>(Wrz_W, WrzT, 512, 512);
  k_transpose<<<512,  256, 0, stream>>>(Wn_W,  WnT,  512, 256);
  k_transpose<<<4,    256, 0, stream>>>(g2_W,  g2T,  32,  32);
  k_transpose<<<96,   256, 0, stream>>>(g3_W,  g3T,  32,  768);
  k_transpose<<<64,   256, 0, stream>>>(obs_W, obsWT, 64, 256);
  k_transpose<<<256,  256, 0, stream>>>(enc_W, encWT, 256, 256);
  k_transpose<<<256,  256, 0, stream>>>(pre_W, preWT, 256, 256);
  k_p2<<<256, 256, 0, stream>>>(pred_W, dp_W, P2T);
  k_p1<<<32,  256, 0, stream>>>(pred_W, g1_W, P1T);
  k_cvec<<<1, 256, 0, stream>>>(pred_b, dp_W, g1_W, g1_b, c2f, c1f);

  k_phase1<<<4096, 256, 0, stream>>>(obs, obsWT, encWT, preWT, obs_b, enc_b, pre_b, out);
  k_phase2<<<64, 512, 0, stream>>>(h0, epoch, out, WrzT, WnT, P2T, P1T, g2T, g3T,
                                   c2f, c1f, Wrz_b, Wn_b, g2_b, g3_b, ln_g, ln_b);

  (void)in_sizes; (void)n_in; (void)out_size; (void)ws_size;
}